// Round 4
// baseline (1223.125 us; speedup 1.0000x reference)
//
#include <hip/hip_runtime.h>

typedef unsigned short u16;
typedef __bf16 bf16x8 __attribute__((ext_vector_type(8)));
typedef float f32x4 __attribute__((ext_vector_type(4)));

#define S_LEN 2048
#define D_DIM 2048
#define NH 16
#define DH 128
#define HID 8192

// softmax scale folded into Q projection: 1/sqrt(128) * log2(e)
#define QSCALE 0.1275458f

__device__ __forceinline__ u16 f2bf(float f) {
  unsigned int u = __float_as_uint(f);
  u += 0x7fff + ((u >> 16) & 1);   // round-to-nearest-even
  return (u16)(u >> 16);
}

// async global->LDS, 16 bytes per lane (global_load_lds_dwordx4)
__device__ __forceinline__ void gld16(const u16* g, u16* l) {
  __builtin_amdgcn_global_load_lds(
      (const __attribute__((address_space(1))) unsigned int*)g,
      (__attribute__((address_space(3))) unsigned int*)l, 16, 0, 0);
}

// ---------------------------------------------------------------------------
// Transpose-convert: in [R][C] fp32 -> out [C][R] bf16, batched over blockIdx.z
// ---------------------------------------------------------------------------
__global__ __launch_bounds__(256) void tconv_f2b(const float* __restrict__ in,
                                                 u16* __restrict__ out, int R, int C) {
  __shared__ float tile[32][33];
  size_t boff = (size_t)blockIdx.z * R * C;
  in += boff; out += boff;
  int c0 = blockIdx.x * 32, r0 = blockIdx.y * 32;
  int tx = threadIdx.x, ty = threadIdx.y;
#pragma unroll
  for (int i = 0; i < 32; i += 8) tile[ty + i][tx] = in[(size_t)(r0 + ty + i) * C + c0 + tx];
  __syncthreads();
#pragma unroll
  for (int i = 0; i < 32; i += 8) out[(size_t)(c0 + ty + i) * R + r0 + tx] = f2bf(tile[tx][ty + i]);
}

// bf16 -> bf16 transpose (for V -> V^T)
__global__ __launch_bounds__(256) void tconv_b2b(const u16* __restrict__ in,
                                                 u16* __restrict__ out, int R, int C) {
  __shared__ u16 tile[32][34];
  size_t boff = (size_t)blockIdx.z * R * C;
  in += boff; out += boff;
  int c0 = blockIdx.x * 32, r0 = blockIdx.y * 32;
  int tx = threadIdx.x, ty = threadIdx.y;
#pragma unroll
  for (int i = 0; i < 32; i += 8) tile[ty + i][tx] = in[(size_t)(r0 + ty + i) * C + c0 + tx];
  __syncthreads();
#pragma unroll
  for (int i = 0; i < 32; i += 8) out[(size_t)(c0 + ty + i) * R + r0 + tx] = tile[tx][ty + i];
}

// ---------------------------------------------------------------------------
// RMSNorm: per-row (D=2048), writes fp32 (optional) and bf16
// ---------------------------------------------------------------------------
__global__ __launch_bounds__(256) void rmsnorm_kernel(const float* __restrict__ x,
                                                      const float* __restrict__ g,
                                                      float* __restrict__ xf,
                                                      u16* __restrict__ xb) {
  int row = blockIdx.x;
  int t = threadIdx.x;
  const float4* xr = (const float4*)(x + (size_t)row * D_DIM);
  float4 v0 = xr[t];
  float4 v1 = xr[t + 256];
  float ss = v0.x * v0.x + v0.y * v0.y + v0.z * v0.z + v0.w * v0.w +
             v1.x * v1.x + v1.y * v1.y + v1.z * v1.z + v1.w * v1.w;
#pragma unroll
  for (int o = 1; o < 64; o <<= 1) ss += __shfl_xor(ss, o, 64);
  __shared__ float wss[4];
  if ((t & 63) == 0) wss[t >> 6] = ss;
  __syncthreads();
  float tot = wss[0] + wss[1] + wss[2] + wss[3];
  float rs = rsqrtf(tot * (1.0f / D_DIM) + 1e-6f);
  const float4* gr = (const float4*)g;
  float4 g0 = gr[t], g1 = gr[t + 256];
  float4 o0, o1;
  o0.x = v0.x * rs * g0.x; o0.y = v0.y * rs * g0.y; o0.z = v0.z * rs * g0.z; o0.w = v0.w * rs * g0.w;
  o1.x = v1.x * rs * g1.x; o1.y = v1.y * rs * g1.y; o1.z = v1.z * rs * g1.z; o1.w = v1.w * rs * g1.w;
  if (xf) {
    float4* xfr = (float4*)(xf + (size_t)row * D_DIM);
    xfr[t] = o0; xfr[t + 256] = o1;
  }
  ushort4 b0, b1;
  b0.x = f2bf(o0.x); b0.y = f2bf(o0.y); b0.z = f2bf(o0.z); b0.w = f2bf(o0.w);
  b1.x = f2bf(o1.x); b1.y = f2bf(o1.y); b1.z = f2bf(o1.z); b1.w = f2bf(o1.w);
  ushort4* xbr = (ushort4*)(xb + (size_t)row * D_DIM);
  xbr[t] = b0; xbr[t + 256] = b1;
}

// ---------------------------------------------------------------------------
// lambda[h] = exp(lq1.lk1) - exp(lq2.lk2) + 0.8
// ---------------------------------------------------------------------------
__global__ __launch_bounds__(256) void lam_kernel(const float* __restrict__ lq1,
                                                  const float* __restrict__ lk1,
                                                  const float* __restrict__ lq2,
                                                  const float* __restrict__ lk2,
                                                  float* __restrict__ lamw) {
  int t = threadIdx.x;
  int h = t >> 4, i = (t & 15) << 3;
  float d1 = 0.f, d2 = 0.f;
#pragma unroll
  for (int j = 0; j < 8; j++) {
    d1 += lq1[h * DH + i + j] * lk1[h * DH + i + j];
    d2 += lq2[h * DH + i + j] * lk2[h * DH + i + j];
  }
#pragma unroll
  for (int o = 1; o < 16; o <<= 1) { d1 += __shfl_xor(d1, o, 64); d2 += __shfl_xor(d2, o, 64); }
  if ((t & 15) == 0) lamw[h] = __expf(d1) - __expf(d2) + 0.8f;
}

// ---------------------------------------------------------------------------
// m97-style GEMM: C[M,N] = A[M,K] @ Bt[N,K]^T, bf16 in, BM=128, BK=32.
// global_load_lds width-16 staging; unpadded LDS [rows][32].
// MODE 0: bf16 out (z-batched via sBt/sC); epilogue *qmul when blockIdx.z<zcut
// MODE 1: fp32 out = acc + res (res = const float*)
// MODE 3: bf16 out = silu(g1) * acc  (res = const u16* g1, bf16)
// BN: 128 (waves own 64x64 -> 64 acc regs) or 64 (waves own 64x32)
// NOTE: dual-accumulator (MODE2) removed -- 128 acc regs drops to 1 wave/SIMD
// on the unified VGPR/AGPR file (R3: occupancy 11%, MfmaUtil 17%).
// ---------------------------------------------------------------------------
template <int MODE, int BN>
__global__ __launch_bounds__(256) void gemm_a(const u16* __restrict__ A,
                                              const u16* __restrict__ Bt,
                                              void* __restrict__ Cout,
                                              const void* __restrict__ res,
                                              int M, int N, int K, long sBt, long sC,
                                              float qmul, int zcut) {
  constexpr int BM = 128, BK = 32;
  constexpr int JF = BN / 32;  // j-frags per wave
  __shared__ __align__(16) u16 As[BM * BK];
  __shared__ __align__(16) u16 Bs[BN * BK];
  const int t = threadIdx.x;
  const int lane = t & 63, wid = t >> 6;
  const int wm = (wid >> 1) * 64, wn = (wid & 1) * (BN / 2);
  const int fr = lane & 15, fq = lane >> 4;
  const int m0 = blockIdx.y * BM, n0 = blockIdx.x * BN;
  const u16* bt = Bt + (long)blockIdx.z * sBt;
  f32x4 acc[4][JF] = {};
  const int sr = t >> 2, sc = (t & 3) << 3;   // 16B-chunk row/col
  const u16* aG = A + (long)(m0 + sr) * K + sc;
  const u16* bG = bt + (long)(n0 + sr) * K + sc;
  u16* aL = &As[t * 8];
  u16* bL = &Bs[t * 8];

  for (int k0 = 0; k0 < K; k0 += BK) {
    __syncthreads();   // prev iteration's ds_reads done before overwrite
    gld16(aG + k0, aL);
    gld16(aG + (long)64 * K + k0, aL + 64 * BK);
    gld16(bG + k0, bL);
    if (BN == 128) gld16(bG + (long)64 * K + k0, bL + 64 * BK);
    __syncthreads();   // drains vmcnt (async LDS writes) before frag reads
    bf16x8 af[4], bfr[JF];
#pragma unroll
    for (int i = 0; i < 4; i++) af[i] = *(const bf16x8*)&As[(wm + i * 16 + fr) * BK + fq * 8];
#pragma unroll
    for (int j = 0; j < JF; j++) bfr[j] = *(const bf16x8*)&Bs[(wn + j * 16 + fr) * BK + fq * 8];
#pragma unroll
    for (int i = 0; i < 4; i++)
#pragma unroll
      for (int j = 0; j < JF; j++)
        acc[i][j] = __builtin_amdgcn_mfma_f32_16x16x32_bf16(af[i], bfr[j], acc[i][j], 0, 0, 0);
  }

  const float cmul = (MODE == 0 && (int)blockIdx.z < zcut) ? qmul : 1.0f;
#pragma unroll
  for (int i = 0; i < 4; i++)
#pragma unroll
    for (int j = 0; j < JF; j++) {
      int row0 = m0 + wm + i * 16 + (fq << 2);
      int col = n0 + wn + j * 16 + fr;
#pragma unroll
      for (int r = 0; r < 4; r++) {
        long idx = (long)(row0 + r) * N + col;
        float v = acc[i][j][r];
        if (MODE == 0) {
          ((u16*)Cout + (long)blockIdx.z * sC)[idx] = f2bf(v * cmul);
        } else if (MODE == 1) {
          ((float*)Cout)[idx] = v + ((const float*)res)[idx];
        } else {  // MODE 3
          float gv = __uint_as_float((unsigned int)((const u16*)res)[idx] << 16);
          float sg = gv / (1.0f + __expf(-gv));
          ((u16*)Cout)[idx] = f2bf(sg * v);
        }
      }
    }
}

// ---------------------------------------------------------------------------
// Differential flash attention, static softmax (scores bounded; no max track).
// Q pre-scaled by 1/sqrt(DH)*log2e at projection -> p = exp2(s), single v_exp.
// kt-tile = 64 (half the barriers of kt=32); single per-wave P buffer reused
// sequentially for P1/P2. Denominator from matrix pipe (P x ones MFMA).
// q1,q2,k1,k2: [H][S][DH] bf16;  vt: [H][DH][S] bf16;  o: [S][H*DH] bf16
// ---------------------------------------------------------------------------
#define LDK 136
#define LDV 72
#define LDP 72

__global__ __launch_bounds__(256) void flash_attn(const u16* __restrict__ q1g,
                                                  const u16* __restrict__ q2g,
                                                  const u16* __restrict__ k1g,
                                                  const u16* __restrict__ k2g,
                                                  const u16* __restrict__ vtg,
                                                  const float* __restrict__ lamw,
                                                  u16* __restrict__ og) {
  __shared__ __align__(16) u16 Ks1[64 * LDK];     // 17408 B
  __shared__ __align__(16) u16 Ks2[64 * LDK];     // 17408 B
  __shared__ __align__(16) u16 Vs[128 * LDV];     // 18432 B
  __shared__ __align__(16) u16 Ps[4 * 16 * LDP];  //  9216 B  (62.5 KB total)
  int h = blockIdx.y, qt = blockIdx.x;
  size_t hoff = (size_t)h * S_LEN * DH;
  const u16* q1 = q1g + hoff;
  const u16* q2 = q2g + hoff;
  const u16* k1 = k1g + hoff;
  const u16* k2 = k2g + hoff;
  const u16* vt = vtg + hoff;
  int t = threadIdx.x, wid = t >> 6, lane = t & 63;
  int fr = lane & 15, fq = lane >> 4;
  int qrow = qt * 64 + wid * 16 + fr;
  bf16x8 qf1[4], qf2[4];
#pragma unroll
  for (int ks = 0; ks < 4; ks++) {
    qf1[ks] = *(const bf16x8*)&q1[(size_t)qrow * DH + ks * 32 + fq * 8];
    qf2[ks] = *(const bf16x8*)&q2[(size_t)qrow * DH + ks * 32 + fq * 8];
  }
  bf16x8 ones;
#pragma unroll
  for (int i = 0; i < 8; i++) ones[i] = (__bf16)1.0f;

  f32x4 O1[8] = {};
  f32x4 O2[8] = {};
  f32x4 L1 = {};
  f32x4 L2 = {};
  int kr = t >> 4, kc = (t & 15) << 3;   // K staging: 16 rows x 128 cols per pass
  int vr = t >> 3, vc = (t & 7) << 3;    // V staging: 32 rows x 64 cols per pass
  u16* myP = &Ps[wid * 16 * LDP];

  for (int kt = 0; kt < S_LEN; kt += 64) {
    uint4 ka1[4], ka2[4], va[4];
#pragma unroll
    for (int j = 0; j < 4; j++) {
      ka1[j] = *(const uint4*)&k1[(size_t)(kt + kr + 16 * j) * DH + kc];
      ka2[j] = *(const uint4*)&k2[(size_t)(kt + kr + 16 * j) * DH + kc];
      va[j] = *(const uint4*)&vt[(size_t)(vr + 32 * j) * S_LEN + kt + vc];
    }
    __syncthreads();
#pragma unroll
    for (int j = 0; j < 4; j++) {
      *(uint4*)&Ks1[(kr + 16 * j) * LDK + kc] = ka1[j];
      *(uint4*)&Ks2[(kr + 16 * j) * LDK + kc] = ka2[j];
      *(uint4*)&Vs[(vr + 32 * j) * LDV + vc] = va[j];
    }
    __syncthreads();

    f32x4 s1[4] = {};
    f32x4 s2[4] = {};
#pragma unroll
    for (int nf = 0; nf < 4; nf++)
#pragma unroll
      for (int ks = 0; ks < 4; ks++) {
        bf16x8 b1v = *(const bf16x8*)&Ks1[(nf * 16 + fr) * LDK + ks * 32 + fq * 8];
        s1[nf] = __builtin_amdgcn_mfma_f32_16x16x32_bf16(qf1[ks], b1v, s1[nf], 0, 0, 0);
        bf16x8 b2v = *(const bf16x8*)&Ks2[(nf * 16 + fr) * LDK + ks * 32 + fq * 8];
        s2[nf] = __builtin_amdgcn_mfma_f32_16x16x32_bf16(qf2[ks], b2v, s2[nf], 0, 0, 0);
      }

    // ---- P1 round trip + PV1 ----
#pragma unroll
    for (int nf = 0; nf < 4; nf++)
#pragma unroll
      for (int r = 0; r < 4; r++)
        myP[(fq * 4 + r) * LDP + nf * 16 + fr] = f2bf(exp2f(s1[nf][r]));
    asm volatile("s_waitcnt lgkmcnt(0)" ::: "memory");
    {
      bf16x8 pa0 = *(const bf16x8*)&myP[fr * LDP + fq * 8];
      bf16x8 pa1 = *(const bf16x8*)&myP[fr * LDP + 32 + fq * 8];
      L1 = __builtin_amdgcn_mfma_f32_16x16x32_bf16(pa0, ones, L1, 0, 0, 0);
      L1 = __builtin_amdgcn_mfma_f32_16x16x32_bf16(pa1, ones, L1, 0, 0, 0);
#pragma unroll
      for (int f = 0; f < 8; f++) {
        bf16x8 bv0 = *(const bf16x8*)&Vs[(f * 16 + fr) * LDV + fq * 8];
        bf16x8 bv1 = *(const bf16x8*)&Vs[(f * 16 + fr) * LDV + 32 + fq * 8];
        O1[f] = __builtin_amdgcn_mfma_f32_16x16x32_bf16(pa0, bv0, O1[f], 0, 0, 0);
        O1[f] = __builtin_amdgcn_mfma_f32_16x16x32_bf16(pa1, bv1, O1[f], 0, 0, 0);
      }
    }
    asm volatile("s_waitcnt lgkmcnt(0)" ::: "memory");  // P1 reads drained before reuse
    // ---- P2 round trip + PV2 ----
#pragma unroll
    for (int nf = 0; nf < 4; nf++)
#pragma unroll
      for (int r = 0; r < 4; r++)
        myP[(fq * 4 + r) * LDP + nf * 16 + fr] = f2bf(exp2f(s2[nf][r]));
    asm volatile("s_waitcnt lgkmcnt(0)" ::: "memory");
    {
      bf16x8 pa0 = *(const bf16x8*)&myP[fr * LDP + fq * 8];
      bf16x8 pa1 = *(const bf16x8*)&myP[fr * LDP + 32 + fq * 8];
      L2 = __builtin_amdgcn_mfma_f32_16x16x32_bf16(pa0, ones, L2, 0, 0, 0);
      L2 = __builtin_amdgcn_mfma_f32_16x16x32_bf16(pa1, ones, L2, 0, 0, 0);
#pragma unroll
      for (int f = 0; f < 8; f++) {
        bf16x8 bv0 = *(const bf16x8*)&Vs[(f * 16 + fr) * LDV + fq * 8];
        bf16x8 bv1 = *(const bf16x8*)&Vs[(f * 16 + fr) * LDV + 32 + fq * 8];
        O2[f] = __builtin_amdgcn_mfma_f32_16x16x32_bf16(pa0, bv0, O2[f], 0, 0, 0);
        O2[f] = __builtin_amdgcn_mfma_f32_16x16x32_bf16(pa1, bv1, O2[f], 0, 0, 0);
      }
    }
    asm volatile("s_waitcnt lgkmcnt(0)" ::: "memory");  // P2 reads drained before next iter
  }

  float lam = lamw[h];
#pragma unroll
  for (int r = 0; r < 4; r++) {
    float i1 = 1.0f / L1[r], i2 = lam / L2[r];
#pragma unroll
    for (int f = 0; f < 8; f++) {
      float val = O1[f][r] * i1 - O2[f][r] * i2;
      og[(size_t)(qt * 64 + wid * 16 + fq * 4 + r) * (NH * DH) + h * DH + f * 16 + fr] =
          f2bf(val);
    }
  }
}

// ---------------------------------------------------------------------------
extern "C" void kernel_launch(void* const* d_in, const int* in_sizes, int n_in,
                              void* d_out, int out_size, void* d_ws, size_t ws_size,
                              hipStream_t stream) {
  const float* x = (const float*)d_in[0];
  const float* g = (const float*)d_in[1];
  const float* Wq1 = (const float*)d_in[2];
  const float* Wq2 = (const float*)d_in[3];
  const float* Wk1 = (const float*)d_in[4];
  const float* Wk2 = (const float*)d_in[5];
  const float* Wv = (const float*)d_in[6];
  const float* lq1 = (const float*)d_in[7];
  const float* lk1 = (const float*)d_in[8];
  const float* lq2 = (const float*)d_in[9];
  const float* lk2 = (const float*)d_in[10];
  const float* Wo = (const float*)d_in[11];
  const float* W1 = (const float*)d_in[12];
  const float* W2 = (const float*)d_in[13];
  const float* W3 = (const float*)d_in[14];

  char* ws = (char*)d_ws;
  size_t off = 0;
  auto alloc = [&](size_t b) {
    char* p = ws + off;
    off += (b + 255) & ~(size_t)255;
    return p;
  };
  const size_t PROJ_B = (size_t)NH * DH * D_DIM * 2;  // 8.39 MB, 256-aligned
  u16* wq1t = (u16*)alloc(PROJ_B);
  u16* wq2t = (u16*)alloc(PROJ_B);
  u16* wk1t = (u16*)alloc(PROJ_B);
  u16* wk2t = (u16*)alloc(PROJ_B);
  u16* wvt = (u16*)alloc(PROJ_B);
  u16* wot = (u16*)alloc((size_t)D_DIM * NH * DH * 2);
  u16* w1t = (u16*)alloc((size_t)HID * D_DIM * 2);
  u16* w2t = (u16*)alloc((size_t)HID * D_DIM * 2);
  u16* w3t = (u16*)alloc((size_t)D_DIM * HID * 2);
  u16* xnb = (u16*)alloc((size_t)S_LEN * D_DIM * 2);
  float* xnf = (float*)alloc((size_t)S_LEN * D_DIM * 4);
  // 5 proj outputs contiguous (q1,q2,k1,k2,v) -- 41.9 MB; reused as g1 in FFN
  u16* q1b = (u16*)alloc(PROJ_B);
  u16* q2b = (u16*)alloc(PROJ_B);
  u16* k1b = (u16*)alloc(PROJ_B);
  u16* k2b = (u16*)alloc(PROJ_B);
  u16* vb = (u16*)alloc(PROJ_B);
  u16* vtb = (u16*)alloc(PROJ_B);
  float* lamw = (float*)alloc(NH * 4);
  u16* oa = (u16*)alloc((size_t)S_LEN * NH * DH * 2);
  float* hf = (float*)alloc((size_t)S_LEN * D_DIM * 4);
  u16* zb = (u16*)alloc((size_t)S_LEN * D_DIM * 2);
  u16* ffb = (u16*)alloc((size_t)S_LEN * HID * 2);
  if (off > ws_size) return;  // workspace too small: out stays zero -> loud failure

  dim3 tpb(32, 8);
  // weight transposes (fp32 -> bf16, [K,N] -> [N,K])
  tconv_f2b<<<dim3(DH / 32, D_DIM / 32, NH), tpb, 0, stream>>>(Wq1, wq1t, D_DIM, DH);
  tconv_f2b<<<dim3(DH / 32, D_DIM / 32, NH), tpb, 0, stream>>>(Wq2, wq2t, D_DIM, DH);
  tconv_f2b<<<dim3(DH / 32, D_DIM / 32, NH), tpb, 0, stream>>>(Wk1, wk1t, D_DIM, DH);
  tconv_f2b<<<dim3(DH / 32, D_DIM / 32, NH), tpb, 0, stream>>>(Wk2, wk2t, D_DIM, DH);
  tconv_f2b<<<dim3(DH / 32, D_DIM / 32, NH), tpb, 0, stream>>>(Wv, wvt, D_DIM, DH);
  tconv_f2b<<<dim3(D_DIM / 32, (NH * DH) / 32, 1), tpb, 0, stream>>>(Wo, wot, NH * DH, D_DIM);
  tconv_f2b<<<dim3(HID / 32, D_DIM / 32, 1), tpb, 0, stream>>>(W1, w1t, D_DIM, HID);
  tconv_f2b<<<dim3(HID / 32, D_DIM / 32, 1), tpb, 0, stream>>>(W2, w2t, D_DIM, HID);
  tconv_f2b<<<dim3(D_DIM / 32, HID / 32, 1), tpb, 0, stream>>>(W3, w3t, HID, D_DIM);

  rmsnorm_kernel<<<S_LEN, 256, 0, stream>>>(x, g, xnf, xnb);
  lam_kernel<<<1, 256, 0, stream>>>(lq1, lk1, lq2, lk2, lamw);

  // all 5 projections in ONE z-batched launch; q tensors (z<32) pre-scaled
  long sB = (long)DH * D_DIM, sC = (long)S_LEN * DH;
  gemm_a<0, 128><<<dim3(1, S_LEN / 128, 80), 256, 0, stream>>>(
      xnb, wq1t, q1b, nullptr, S_LEN, DH, D_DIM, sB, sC, QSCALE, 32);
  // V -> V^T per head
  tconv_b2b<<<dim3(DH / 32, S_LEN / 32, NH), tpb, 0, stream>>>(vb, vtb, S_LEN, DH);

  flash_attn<<<dim3(S_LEN / 64, NH), 256, 0, stream>>>(q1b, q2b, k1b, k2b, vtb, lamw, oa);

  // h = o @ Wo + xn  (fp32)
  gemm_a<1, 64><<<dim3(D_DIM / 64, S_LEN / 128, 1), 256, 0, stream>>>(
      oa, wot, hf, xnf, S_LEN, D_DIM, NH * DH, 0, 0, 1.0f, 0);
  // z = rmsnorm(h)
  rmsnorm_kernel<<<S_LEN, 256, 0, stream>>>(hf, g, nullptr, zb);
  // FFN as two m97-shape GEMMs (64 acc regs each; avoids the R3 occupancy cliff)
  u16* g1b = q1b;  // reuse dead attention scratch (q1b..vb = 41.9 MB >= 33.6 MB)
  gemm_a<0, 128><<<dim3(HID / 128, S_LEN / 128, 1), 256, 0, stream>>>(
      zb, w1t, g1b, nullptr, S_LEN, HID, D_DIM, 0, 0, 1.0f, 0);
  gemm_a<3, 128><<<dim3(HID / 128, S_LEN / 128, 1), 256, 0, stream>>>(
      zb, w2t, ffb, g1b, S_LEN, HID, D_DIM, 0, 0, 1.0f, 0);
  // out = gate @ W3 + h  (fp32)
  gemm_a<1, 64><<<dim3(D_DIM / 64, S_LEN / 128, 1), 256, 0, stream>>>(
      ffb, w3t, d_out, hf, S_LEN, D_DIM, HID, 0, 0, 1.0f, 0);
}

// Round 5
// 1056.768 us; speedup vs baseline: 1.1574x; 1.1574x over previous
//
#include <hip/hip_runtime.h>

typedef unsigned short u16;
typedef __bf16 bf16x8 __attribute__((ext_vector_type(8)));
typedef float f32x4 __attribute__((ext_vector_type(4)));

#define S_LEN 2048
#define D_DIM 2048
#define NH 16
#define DH 128
#define HID 8192

// softmax scale folded into Q projection: 1/sqrt(128) * log2(e)
#define QSCALE 0.1275458f

__device__ __forceinline__ u16 f2bf(float f) {
  unsigned int u = __float_as_uint(f);
  u += 0x7fff + ((u >> 16) & 1);   // round-to-nearest-even
  return (u16)(u >> 16);
}

__device__ __forceinline__ float bf2f(u16 b) {
  return __uint_as_float((unsigned int)b << 16);
}

// async global->LDS, 16 bytes per lane (global_load_lds_dwordx4)
__device__ __forceinline__ void gld16(const u16* g, u16* l) {
  __builtin_amdgcn_global_load_lds(
      (const __attribute__((address_space(1))) unsigned int*)g,
      (__attribute__((address_space(3))) unsigned int*)l, 16, 0, 0);
}

// ---------------------------------------------------------------------------
// Transpose-convert: in [R][C] fp32 -> out [C][R] bf16, batched over blockIdx.z
// ---------------------------------------------------------------------------
__global__ __launch_bounds__(256) void tconv_f2b(const float* __restrict__ in,
                                                 u16* __restrict__ out, int R, int C) {
  __shared__ float tile[32][33];
  size_t boff = (size_t)blockIdx.z * R * C;
  in += boff; out += boff;
  int c0 = blockIdx.x * 32, r0 = blockIdx.y * 32;
  int tx = threadIdx.x, ty = threadIdx.y;
#pragma unroll
  for (int i = 0; i < 32; i += 8) tile[ty + i][tx] = in[(size_t)(r0 + ty + i) * C + c0 + tx];
  __syncthreads();
#pragma unroll
  for (int i = 0; i < 32; i += 8) out[(size_t)(c0 + ty + i) * R + r0 + tx] = f2bf(tile[tx][ty + i]);
}

// bf16 -> bf16 transpose (for V -> V^T)
__global__ __launch_bounds__(256) void tconv_b2b(const u16* __restrict__ in,
                                                 u16* __restrict__ out, int R, int C) {
  __shared__ u16 tile[32][34];
  size_t boff = (size_t)blockIdx.z * R * C;
  in += boff; out += boff;
  int c0 = blockIdx.x * 32, r0 = blockIdx.y * 32;
  int tx = threadIdx.x, ty = threadIdx.y;
#pragma unroll
  for (int i = 0; i < 32; i += 8) tile[ty + i][tx] = in[(size_t)(r0 + ty + i) * C + c0 + tx];
  __syncthreads();
#pragma unroll
  for (int i = 0; i < 32; i += 8) out[(size_t)(c0 + ty + i) * R + r0 + tx] = tile[tx][ty + i];
}

// ---------------------------------------------------------------------------
// RMSNorm: per-row (D=2048), writes fp32 (optional) and bf16
// ---------------------------------------------------------------------------
__global__ __launch_bounds__(256) void rmsnorm_kernel(const float* __restrict__ x,
                                                      const float* __restrict__ g,
                                                      float* __restrict__ xf,
                                                      u16* __restrict__ xb) {
  int row = blockIdx.x;
  int t = threadIdx.x;
  const float4* xr = (const float4*)(x + (size_t)row * D_DIM);
  float4 v0 = xr[t];
  float4 v1 = xr[t + 256];
  float ss = v0.x * v0.x + v0.y * v0.y + v0.z * v0.z + v0.w * v0.w +
             v1.x * v1.x + v1.y * v1.y + v1.z * v1.z + v1.w * v1.w;
#pragma unroll
  for (int o = 1; o < 64; o <<= 1) ss += __shfl_xor(ss, o, 64);
  __shared__ float wss[4];
  if ((t & 63) == 0) wss[t >> 6] = ss;
  __syncthreads();
  float tot = wss[0] + wss[1] + wss[2] + wss[3];
  float rs = rsqrtf(tot * (1.0f / D_DIM) + 1e-6f);
  const float4* gr = (const float4*)g;
  float4 g0 = gr[t], g1 = gr[t + 256];
  float4 o0, o1;
  o0.x = v0.x * rs * g0.x; o0.y = v0.y * rs * g0.y; o0.z = v0.z * rs * g0.z; o0.w = v0.w * rs * g0.w;
  o1.x = v1.x * rs * g1.x; o1.y = v1.y * rs * g1.y; o1.z = v1.z * rs * g1.z; o1.w = v1.w * rs * g1.w;
  if (xf) {
    float4* xfr = (float4*)(xf + (size_t)row * D_DIM);
    xfr[t] = o0; xfr[t + 256] = o1;
  }
  ushort4 b0, b1;
  b0.x = f2bf(o0.x); b0.y = f2bf(o0.y); b0.z = f2bf(o0.z); b0.w = f2bf(o0.w);
  b1.x = f2bf(o1.x); b1.y = f2bf(o1.y); b1.z = f2bf(o1.z); b1.w = f2bf(o1.w);
  ushort4* xbr = (ushort4*)(xb + (size_t)row * D_DIM);
  xbr[t] = b0; xbr[t + 256] = b1;
}

// ---------------------------------------------------------------------------
// lambda[h] = exp(lq1.lk1) - exp(lq2.lk2) + 0.8
// ---------------------------------------------------------------------------
__global__ __launch_bounds__(256) void lam_kernel(const float* __restrict__ lq1,
                                                  const float* __restrict__ lk1,
                                                  const float* __restrict__ lq2,
                                                  const float* __restrict__ lk2,
                                                  float* __restrict__ lamw) {
  int t = threadIdx.x;
  int h = t >> 4, i = (t & 15) << 3;
  float d1 = 0.f, d2 = 0.f;
#pragma unroll
  for (int j = 0; j < 8; j++) {
    d1 += lq1[h * DH + i + j] * lk1[h * DH + i + j];
    d2 += lq2[h * DH + i + j] * lk2[h * DH + i + j];
  }
#pragma unroll
  for (int o = 1; o < 16; o <<= 1) { d1 += __shfl_xor(d1, o, 64); d2 += __shfl_xor(d2, o, 64); }
  if ((t & 15) == 0) lamw[h] = __expf(d1) - __expf(d2) + 0.8f;
}

// ---------------------------------------------------------------------------
// m97-style GEMM: C[M,N] = A[M,K] @ Bt[N,K]^T, bf16 in, BM=128, BK=32.
// global_load_lds width-16 staging; unpadded LDS [rows][32].
// MODE 0: bf16 out (z-batched via sBt/sC); epilogue *qmul when blockIdx.z<zcut
// MODE 1: fp32 out = acc + res (res = const float*)
// MODE 3: bf16 out = silu(g1) * acc  (res = const u16* g1, bf16)
// BN: 128 (waves own 64x64 -> 64 acc regs) or 64 (waves own 64x32)
// NOTE: dual-accumulator removed -- 128 acc regs -> 1 wave/SIMD (R3 cliff).
// ---------------------------------------------------------------------------
template <int MODE, int BN>
__global__ __launch_bounds__(256) void gemm_a(const u16* __restrict__ A,
                                              const u16* __restrict__ Bt,
                                              void* __restrict__ Cout,
                                              const void* __restrict__ res,
                                              int M, int N, int K, long sBt, long sC,
                                              float qmul, int zcut) {
  constexpr int BM = 128, BK = 32;
  constexpr int JF = BN / 32;  // j-frags per wave
  __shared__ __align__(16) u16 As[BM * BK];
  __shared__ __align__(16) u16 Bs[BN * BK];
  const int t = threadIdx.x;
  const int lane = t & 63, wid = t >> 6;
  const int wm = (wid >> 1) * 64, wn = (wid & 1) * (BN / 2);
  const int fr = lane & 15, fq = lane >> 4;
  const int m0 = blockIdx.y * BM, n0 = blockIdx.x * BN;
  const u16* bt = Bt + (long)blockIdx.z * sBt;
  f32x4 acc[4][JF] = {};
  const int sr = t >> 2, sc = (t & 3) << 3;   // 16B-chunk row/col
  const u16* aG = A + (long)(m0 + sr) * K + sc;
  const u16* bG = bt + (long)(n0 + sr) * K + sc;
  u16* aL = &As[t * 8];
  u16* bL = &Bs[t * 8];

  for (int k0 = 0; k0 < K; k0 += BK) {
    __syncthreads();   // prev iteration's ds_reads done before overwrite
    gld16(aG + k0, aL);
    gld16(aG + (long)64 * K + k0, aL + 64 * BK);
    gld16(bG + k0, bL);
    if (BN == 128) gld16(bG + (long)64 * K + k0, bL + 64 * BK);
    __syncthreads();   // drains vmcnt (async LDS writes) before frag reads
    bf16x8 af[4], bfr[JF];
#pragma unroll
    for (int i = 0; i < 4; i++) af[i] = *(const bf16x8*)&As[(wm + i * 16 + fr) * BK + fq * 8];
#pragma unroll
    for (int j = 0; j < JF; j++) bfr[j] = *(const bf16x8*)&Bs[(wn + j * 16 + fr) * BK + fq * 8];
#pragma unroll
    for (int i = 0; i < 4; i++)
#pragma unroll
      for (int j = 0; j < JF; j++)
        acc[i][j] = __builtin_amdgcn_mfma_f32_16x16x32_bf16(af[i], bfr[j], acc[i][j], 0, 0, 0);
  }

  const float cmul = (MODE == 0 && (int)blockIdx.z < zcut) ? qmul : 1.0f;
#pragma unroll
  for (int i = 0; i < 4; i++)
#pragma unroll
    for (int j = 0; j < JF; j++) {
      int row0 = m0 + wm + i * 16 + (fq << 2);
      int col = n0 + wn + j * 16 + fr;
#pragma unroll
      for (int r = 0; r < 4; r++) {
        long idx = (long)(row0 + r) * N + col;
        float v = acc[i][j][r];
        if (MODE == 0) {
          ((u16*)Cout + (long)blockIdx.z * sC)[idx] = f2bf(v * cmul);
        } else if (MODE == 1) {
          ((float*)Cout)[idx] = v + ((const float*)res)[idx];
        } else {  // MODE 3
          float gv = bf2f(((const u16*)res)[idx]);
          float sg = gv / (1.0f + __expf(-gv));
          ((u16*)Cout)[idx] = f2bf(sg * v);
        }
      }
    }
}

// ---------------------------------------------------------------------------
// Differential flash attention, static softmax, SPLIT-K over sequence.
// kt-tile 32, gld16 chunk-major staging (unpadded [chunk][32][32], 2-way bank
// alias only). Each block: 64 q-rows x one head x half the keys. Partial
// unnormalized O (bf16) and L (fp32) written to ws; combined by attn_combine.
// q1,q2,k1,k2: [H][S][DH] bf16;  vt: [H][DH][S] bf16.
// ---------------------------------------------------------------------------
#define LDP 40
#define FSPLIT 2

__global__ __launch_bounds__(256) void flash_attn(const u16* __restrict__ q1g,
                                                  const u16* __restrict__ q2g,
                                                  const u16* __restrict__ k1g,
                                                  const u16* __restrict__ k2g,
                                                  const u16* __restrict__ vtg,
                                                  u16* __restrict__ po1,
                                                  u16* __restrict__ po2,
                                                  float* __restrict__ pl1,
                                                  float* __restrict__ pl2) {
  __shared__ __align__(16) u16 Ks1[4096];          // [4 chunks][32 rows][32 cols] 8 KB
  __shared__ __align__(16) u16 Ks2[4096];          // 8 KB
  __shared__ __align__(16) u16 Vs[4096];           // [128 dh][32 kt] 8 KB
  __shared__ __align__(16) u16 Ps[4 * 2 * 16 * LDP];  // 10 KB  (34.8 KB total)
  int h = blockIdx.y, qt = blockIdx.x, sp = blockIdx.z;
  size_t hoff = (size_t)h * S_LEN * DH;
  const u16* q1 = q1g + hoff;
  const u16* q2 = q2g + hoff;
  const u16* k1 = k1g + hoff;
  const u16* k2 = k2g + hoff;
  const u16* vt = vtg + hoff;
  int t = threadIdx.x, wid = t >> 6, lane = t & 63;
  int fr = lane & 15, fq = lane >> 4;
  int qrow = qt * 64 + wid * 16 + fr;
  bf16x8 qf1[4], qf2[4];
#pragma unroll
  for (int ks = 0; ks < 4; ks++) {
    qf1[ks] = *(const bf16x8*)&q1[(size_t)qrow * DH + ks * 32 + fq * 8];
    qf2[ks] = *(const bf16x8*)&q2[(size_t)qrow * DH + ks * 32 + fq * 8];
  }
  bf16x8 ones;
#pragma unroll
  for (int i = 0; i < 8; i++) ones[i] = (__bf16)1.0f;

  f32x4 O1[8] = {};
  f32x4 O2[8] = {};
  f32x4 L1 = {};
  f32x4 L2 = {};
  // staging thread map (K): chunk c = pass*2 + (t>>7); row=(t&127)>>2; col8=t&3
  const int skrow = (t & 127) >> 2, skcol = (t & 3) << 3, skch = (t >> 7) << 5;
  // staging thread map (V): row = pass*64 + (t>>2); col8 = t&3
  const int svrow = t >> 2, svcol = (t & 3) << 3;
  u16* myP1 = &Ps[(wid * 2 + 0) * 16 * LDP];
  u16* myP2 = &Ps[(wid * 2 + 1) * 16 * LDP];

  const int kt0 = sp * (S_LEN / FSPLIT);
  for (int kt = kt0; kt < kt0 + S_LEN / FSPLIT; kt += 32) {
    __syncthreads();   // prev iter's ds_reads done before DMA overwrite
    gld16(&k1[(size_t)(kt + skrow) * DH + skch + skcol], &Ks1[t * 8]);
    gld16(&k1[(size_t)(kt + skrow) * DH + 64 + skch + skcol], &Ks1[2048 + t * 8]);
    gld16(&k2[(size_t)(kt + skrow) * DH + skch + skcol], &Ks2[t * 8]);
    gld16(&k2[(size_t)(kt + skrow) * DH + 64 + skch + skcol], &Ks2[2048 + t * 8]);
    gld16(&vt[(size_t)svrow * S_LEN + kt + svcol], &Vs[t * 8]);
    gld16(&vt[(size_t)(svrow + 64) * S_LEN + kt + svcol], &Vs[2048 + t * 8]);
    __syncthreads();   // drains vmcnt before fragment reads

    f32x4 s1[2] = {};
    f32x4 s2[2] = {};
#pragma unroll
    for (int nf = 0; nf < 2; nf++)
#pragma unroll
      for (int ks = 0; ks < 4; ks++) {
        bf16x8 b1v = *(const bf16x8*)&Ks1[ks * 1024 + (nf * 16 + fr) * 32 + fq * 8];
        s1[nf] = __builtin_amdgcn_mfma_f32_16x16x32_bf16(qf1[ks], b1v, s1[nf], 0, 0, 0);
        bf16x8 b2v = *(const bf16x8*)&Ks2[ks * 1024 + (nf * 16 + fr) * 32 + fq * 8];
        s2[nf] = __builtin_amdgcn_mfma_f32_16x16x32_bf16(qf2[ks], b2v, s2[nf], 0, 0, 0);
      }

    // static softmax: p = exp2(s) (scale/log2e folded into Q); no max track
#pragma unroll
    for (int nf = 0; nf < 2; nf++)
#pragma unroll
      for (int r = 0; r < 4; r++) {
        myP1[(fq * 4 + r) * LDP + nf * 16 + fr] = f2bf(exp2f(s1[nf][r]));
        myP2[(fq * 4 + r) * LDP + nf * 16 + fr] = f2bf(exp2f(s2[nf][r]));
      }
    asm volatile("s_waitcnt lgkmcnt(0)" ::: "memory");
    bf16x8 pa1 = *(const bf16x8*)&myP1[fr * LDP + fq * 8];
    bf16x8 pa2 = *(const bf16x8*)&myP2[fr * LDP + fq * 8];
    L1 = __builtin_amdgcn_mfma_f32_16x16x32_bf16(pa1, ones, L1, 0, 0, 0);
    L2 = __builtin_amdgcn_mfma_f32_16x16x32_bf16(pa2, ones, L2, 0, 0, 0);
#pragma unroll
    for (int f = 0; f < 8; f++) {
      bf16x8 bv = *(const bf16x8*)&Vs[(f * 16 + fr) * 32 + fq * 8];
      O1[f] = __builtin_amdgcn_mfma_f32_16x16x32_bf16(pa1, bv, O1[f], 0, 0, 0);
      O2[f] = __builtin_amdgcn_mfma_f32_16x16x32_bf16(pa2, bv, O2[f], 0, 0, 0);
    }
  }

  // write unnormalized partials (bf16) + row sums (fp32, fr==0 lanes)
  const int NC = NH * DH;
#pragma unroll
  for (int r = 0; r < 4; r++) {
    int q = qt * 64 + wid * 16 + fq * 4 + r;
    size_t rowb = ((size_t)sp * S_LEN + q) * NC + h * DH;
#pragma unroll
    for (int f = 0; f < 8; f++) {
      po1[rowb + f * 16 + fr] = f2bf(O1[f][r]);
      po2[rowb + f * 16 + fr] = f2bf(O2[f][r]);
    }
    if (fr == 0) {
      pl1[((size_t)sp * NH + h) * S_LEN + q] = L1[r];
      pl2[((size_t)sp * NH + h) * S_LEN + q] = L2[r];
    }
  }
}

// ---------------------------------------------------------------------------
// Combine split partials: o = (O1a+O1b)/(L1a+L1b) - lam*(O2a+O2b)/(L2a+L2b)
// ---------------------------------------------------------------------------
__global__ __launch_bounds__(256) void attn_combine(const u16* __restrict__ po1,
                                                    const u16* __restrict__ po2,
                                                    const float* __restrict__ pl1,
                                                    const float* __restrict__ pl2,
                                                    const float* __restrict__ lamw,
                                                    u16* __restrict__ oa) {
  const int NC = NH * DH;
  size_t gid = (size_t)blockIdx.x * 256 + threadIdx.x;  // one thread = 8 cols
  int q = (int)(gid >> 8);
  int col = (int)(gid & 255) << 3;
  int h = col >> 7;
  size_t i0 = (size_t)q * NC + col;
  size_t i1 = ((size_t)S_LEN + q) * NC + col;
  bf16x8 a1 = *(const bf16x8*)&po1[i0];
  bf16x8 b1 = *(const bf16x8*)&po1[i1];
  bf16x8 a2 = *(const bf16x8*)&po2[i0];
  bf16x8 b2 = *(const bf16x8*)&po2[i1];
  float inv1 = 1.0f / (pl1[h * S_LEN + q] + pl1[(NH + h) * S_LEN + q]);
  float inv2 = lamw[h] / (pl2[h * S_LEN + q] + pl2[(NH + h) * S_LEN + q]);
  u16 outv[8];
#pragma unroll
  for (int i = 0; i < 8; i++) {
    float o1 = (float)a1[i] + (float)b1[i];
    float o2 = (float)a2[i] + (float)b2[i];
    outv[i] = f2bf(o1 * inv1 - o2 * inv2);
  }
  *(uint4*)&oa[i0] = *(const uint4*)outv;
}

// ---------------------------------------------------------------------------
extern "C" void kernel_launch(void* const* d_in, const int* in_sizes, int n_in,
                              void* d_out, int out_size, void* d_ws, size_t ws_size,
                              hipStream_t stream) {
  const float* x = (const float*)d_in[0];
  const float* g = (const float*)d_in[1];
  const float* Wq1 = (const float*)d_in[2];
  const float* Wq2 = (const float*)d_in[3];
  const float* Wk1 = (const float*)d_in[4];
  const float* Wk2 = (const float*)d_in[5];
  const float* Wv = (const float*)d_in[6];
  const float* lq1 = (const float*)d_in[7];
  const float* lk1 = (const float*)d_in[8];
  const float* lq2 = (const float*)d_in[9];
  const float* lk2 = (const float*)d_in[10];
  const float* Wo = (const float*)d_in[11];
  const float* W1 = (const float*)d_in[12];
  const float* W2 = (const float*)d_in[13];
  const float* W3 = (const float*)d_in[14];

  char* ws = (char*)d_ws;
  size_t off = 0;
  auto alloc = [&](size_t b) {
    char* p = ws + off;
    off += (b + 255) & ~(size_t)255;
    return p;
  };
  const size_t PROJ_B = (size_t)NH * DH * D_DIM * 2;  // 8.39 MB, 256-aligned
  // 5 proj weights contiguous (41.9 MB); DEAD after proj GEMM -> reused for
  // the flash split partials (33.6 MB O + 0.5 MB L).
  u16* wq1t = (u16*)alloc(PROJ_B);
  u16* wq2t = (u16*)alloc(PROJ_B);
  u16* wk1t = (u16*)alloc(PROJ_B);
  u16* wk2t = (u16*)alloc(PROJ_B);
  u16* wvt = (u16*)alloc(PROJ_B);
  u16* wot = (u16*)alloc((size_t)D_DIM * NH * DH * 2);
  u16* w1t = (u16*)alloc((size_t)HID * D_DIM * 2);
  u16* w2t = (u16*)alloc((size_t)HID * D_DIM * 2);
  u16* w3t = (u16*)alloc((size_t)D_DIM * HID * 2);
  u16* xnb = (u16*)alloc((size_t)S_LEN * D_DIM * 2);
  float* xnf = (float*)alloc((size_t)S_LEN * D_DIM * 4);
  // 5 proj outputs contiguous (q1,q2,k1,k2,v); q1b.. reused as g1 in FFN
  u16* q1b = (u16*)alloc(PROJ_B);
  u16* q2b = (u16*)alloc(PROJ_B);
  u16* k1b = (u16*)alloc(PROJ_B);
  u16* k2b = (u16*)alloc(PROJ_B);
  u16* vb = (u16*)alloc(PROJ_B);
  u16* vtb = (u16*)alloc(PROJ_B);
  float* lamw = (float*)alloc(NH * 4);
  u16* oa = (u16*)alloc((size_t)S_LEN * NH * DH * 2);
  float* hf = (float*)alloc((size_t)S_LEN * D_DIM * 4);
  u16* zb = (u16*)alloc((size_t)S_LEN * D_DIM * 2);
  u16* ffb = (u16*)alloc((size_t)S_LEN * HID * 2);
  if (off > ws_size) return;  // workspace too small: out stays zero -> loud failure

  // flash split partials overlay the dead proj-weight region
  u16* po1 = wq1t;                                          // 2*S*2048 bf16 = 16.8 MB
  u16* po2 = po1 + (size_t)FSPLIT * S_LEN * NH * DH;        // 16.8 MB
  float* pl1 = (float*)(po2 + (size_t)FSPLIT * S_LEN * NH * DH);
  float* pl2 = pl1 + (size_t)FSPLIT * NH * S_LEN;

  dim3 tpb(32, 8);
  // weight transposes (fp32 -> bf16, [K,N] -> [N,K])
  tconv_f2b<<<dim3(DH / 32, D_DIM / 32, NH), tpb, 0, stream>>>(Wq1, wq1t, D_DIM, DH);
  tconv_f2b<<<dim3(DH / 32, D_DIM / 32, NH), tpb, 0, stream>>>(Wq2, wq2t, D_DIM, DH);
  tconv_f2b<<<dim3(DH / 32, D_DIM / 32, NH), tpb, 0, stream>>>(Wk1, wk1t, D_DIM, DH);
  tconv_f2b<<<dim3(DH / 32, D_DIM / 32, NH), tpb, 0, stream>>>(Wk2, wk2t, D_DIM, DH);
  tconv_f2b<<<dim3(DH / 32, D_DIM / 32, NH), tpb, 0, stream>>>(Wv, wvt, D_DIM, DH);
  tconv_f2b<<<dim3(D_DIM / 32, (NH * DH) / 32, 1), tpb, 0, stream>>>(Wo, wot, NH * DH, D_DIM);
  tconv_f2b<<<dim3(HID / 32, D_DIM / 32, 1), tpb, 0, stream>>>(W1, w1t, D_DIM, HID);
  tconv_f2b<<<dim3(HID / 32, D_DIM / 32, 1), tpb, 0, stream>>>(W2, w2t, D_DIM, HID);
  tconv_f2b<<<dim3(D_DIM / 32, HID / 32, 1), tpb, 0, stream>>>(W3, w3t, HID, D_DIM);

  rmsnorm_kernel<<<S_LEN, 256, 0, stream>>>(x, g, xnf, xnb);
  lam_kernel<<<1, 256, 0, stream>>>(lq1, lk1, lq2, lk2, lamw);

  // all 5 projections in ONE z-batched launch; q tensors (z<32) pre-scaled
  long sB = (long)DH * D_DIM, sC = (long)S_LEN * DH;
  gemm_a<0, 128><<<dim3(1, S_LEN / 128, 80), 256, 0, stream>>>(
      xnb, wq1t, q1b, nullptr, S_LEN, DH, D_DIM, sB, sC, QSCALE, 32);
  // V -> V^T per head
  tconv_b2b<<<dim3(DH / 32, S_LEN / 32, NH), tpb, 0, stream>>>(vb, vtb, S_LEN, DH);

  flash_attn<<<dim3(S_LEN / 64, NH, FSPLIT), 256, 0, stream>>>(
      q1b, q2b, k1b, k2b, vtb, po1, po2, pl1, pl2);
  attn_combine<<<(S_LEN * NH * DH / 8) / 256, 256, 0, stream>>>(
      po1, po2, pl1, pl2, lamw, oa);

  // h = o @ Wo + xn  (fp32)
  gemm_a<1, 64><<<dim3(D_DIM / 64, S_LEN / 128, 1), 256, 0, stream>>>(
      oa, wot, hf, xnf, S_LEN, D_DIM, NH * DH, 0, 0, 1.0f, 0);
  // z = rmsnorm(h)
  rmsnorm_kernel<<<S_LEN, 256, 0, stream>>>(hf, g, nullptr, zb);
  // FFN as two m97-shape GEMMs (64 acc regs each; avoids the R3 occupancy cliff)
  u16* g1b = q1b;  // reuse dead attention scratch (q1b..vb = 41.9 MB >= 33.6 MB)
  gemm_a<0, 128><<<dim3(HID / 128, S_LEN / 128, 1), 256, 0, stream>>>(
      zb, w1t, g1b, nullptr, S_LEN, HID, D_DIM, 0, 0, 1.0f, 0);
  gemm_a<3, 128><<<dim3(HID / 128, S_LEN / 128, 1), 256, 0, stream>>>(
      zb, w2t, ffb, g1b, S_LEN, HID, D_DIM, 0, 0, 1.0f, 0);
  // out = gate @ W3 + h  (fp32)
  gemm_a<1, 64><<<dim3(D_DIM / 64, S_LEN / 128, 1), 256, 0, stream>>>(
      ffb, w3t, d_out, hf, S_LEN, D_DIM, HID, 0, 0, 1.0f, 0);
}